// Round 12
// baseline (725.193 us; speedup 1.0000x reference)
//
#include <hip/hip_runtime.h>
#include <hip/hip_bf16.h>

typedef __attribute__((ext_vector_type(8))) short short8;
typedef __attribute__((ext_vector_type(4))) float f32x4;

#define BM 128
#define BN 128
#define BK 32
#define KDIM 7168
#define NDIM 18432
#define SN 56            // KDIM/128 scale cols
#define NT32 224         // KDIM/BK
#define SPLITK 2
#define STEPS (NT32 / SPLITK)   // 112 per block (even)

static __device__ __forceinline__ short bfb(float f) {
    __hip_bfloat16 h = __float2bfloat16(f);
    return __builtin_bit_cast(short, h);
}

// ---- pre-kernel: A fp32 -> bf16, BK=32-tile-major, inverse-XOR-swizzled so
// the GEMM stages it with global_load_lds (linear dest) and reads with XOR.
// swizzle: chunk_in_row = slot ^ ((r>>1)&3)  (conflict-free for 64B rows)
extern "C" __global__ void __launch_bounds__(256)
a_permute(const float* __restrict__ A, __hip_bfloat16* __restrict__ Abt, int nunits) {
    int g = blockIdx.x * blockDim.x + threadIdx.x;
    if (g >= nunits) return;
    int u    = g & 511;
    int t    = g >> 9;
    int ktt  = t % NT32;
    int mt   = t / NT32;
    int r    = u >> 2;
    int slot = u & 3;
    int row  = mt * BM + r;
    int col  = ktt * BK + ((slot ^ ((r >> 1) & 3)) << 3);
    const float* p = A + (size_t)row * KDIM + col;
    f32x4 v0 = *(const f32x4*)p;
    f32x4 v1 = *(const f32x4*)(p + 4);
    short8 o;
#pragma unroll
    for (int j = 0; j < 4; ++j) { o[j] = bfb(v0[j]); o[j + 4] = bfb(v1[j]); }
    *(short8*)(Abt + (size_t)g * 8) = o;
}

// AMODE 1: A via global_load_lds from pre-permuted Abt.  AMODE 0: reg-staged.
// Split-K=2 over blockIdx.y; partial sums atomicAdd'ed into zeroed C.
template <int AMODE>
__global__ void __launch_bounds__(512, 8)
fp8lin_gemm(const float* __restrict__ A,          // [M][K] fp32
            const char*  __restrict__ Abt,        // pre-permuted bf16 tiles (ws)
            const float* __restrict__ W,          // [N][K] fp32
            const float* __restrict__ S,          // [N/128][K/128]
            float* __restrict__ C,                // [M][N], pre-zeroed
            int M)
{
    const int ntile_m = M / BM;            // 4
    const int ntile_n = NDIM / BN;         // 144
    const int nwg = ntile_m * ntile_n;     // 576

    int orig = (int)blockIdx.x;
    int q = nwg >> 3;
    int lid = (orig & 7) * q + (orig >> 3);

    const int tm = lid % ntile_m;
    const int tn = lid / ntile_m;
    const int kh = blockIdx.y;             // K-half
    const int m0 = tm * BM;
    const int n0 = tn * BN;
    const int g0 = kh * STEPS;             // first global K-step

    const int tid  = threadIdx.x;
    const int lane = tid & 63;
    const int wid  = tid >> 6;      // 8 waves: 2(M) x 4(N), wave tile 64x32
    const int wm   = wid >> 2;
    const int wn   = wid & 3;

    __shared__ char ldsA[2][BM * BK * 2];   // bf16, 8 KiB each
    __shared__ char ldsW[2][BN * BK * 2];   // bf16, 8 KiB each (32 KiB total)

    // W staging: one 16B unit per thread: r=tid>>2, sl=tid&3.
    // LDS write LINEAR (tid*16); XOR lives in the global source col.
    const int st_r  = tid >> 2;
    const int st_sl = tid & 3;
    const int st_gc = (st_sl ^ ((st_r >> 1) & 3)) << 3;

    const float* Afp = A + (size_t)m0 * KDIM;
    const float* Wb  = W + (size_t)n0 * KDIM + (size_t)st_r * KDIM + st_gc;

    auto AGL = [&](int gstep, int buf) {   // async A: global -> LDS, 1 inst/wave
        const char* src = Abt + (((size_t)(tm * NT32 + gstep)) << 13);
        int ub = wid * 64 + lane;
        __builtin_amdgcn_global_load_lds(
            (const __attribute__((address_space(1))) void*)(src + (size_t)ub * 16),
            (__attribute__((address_space(3))) void*)(&ldsA[buf][ub * 16]),
            16, 0, 0);
    };

    auto WLD = [&](int gstep, f32x4* dst) {   // W fp32 -> regs (2 x dwordx4)
        const float* pw = Wb + gstep * BK;
        dst[0] = *(const f32x4*)pw;
        dst[1] = *(const f32x4*)(pw + 4);
    };

    auto ALD = [&](int gstep, f32x4* dst) {   // AMODE 0: A fp32 -> regs
        const float* pa = Afp + (size_t)st_r * KDIM + gstep * BK + st_gc;
        dst[0] = *(const f32x4*)pa;
        dst[1] = *(const f32x4*)(pa + 4);
    };

    auto WRITES = [&](int buf, const f32x4* rw_, const f32x4* ra_, float s) {
        short8 vw;
#pragma unroll
        for (int j = 0; j < 4; ++j) {
            vw[j]     = bfb(rw_[0][j] * s);
            vw[j + 4] = bfb(rw_[1][j] * s);
        }
        *(short8*)(&ldsW[buf][tid * 16]) = vw;
        if (AMODE == 0) {
            short8 va;
#pragma unroll
            for (int j = 0; j < 4; ++j) {
                va[j]     = bfb(ra_[0][j]);
                va[j + 4] = bfb(ra_[1][j]);
            }
            *(short8*)(&ldsA[buf][tid * 16]) = va;
        }
    };

    f32x4 acc[4][2];
#pragma unroll
    for (int i = 0; i < 4; ++i)
#pragma unroll
        for (int j = 0; j < 2; ++j)
            acc[i][j] = f32x4{0.f, 0.f, 0.f, 0.f};

    const int l15 = lane & 15;
    const int lq  = lane >> 4;      // 16B chunk 0..3 along BK=32

    auto COMPUTE = [&](int buf) {
        const char* la = ldsA[buf];
        const char* lb = ldsW[buf];
        short8 af[4], bq[2];
#pragma unroll
        for (int i = 0; i < 4; ++i) {
            int r = wm * 64 + i * 16 + l15;
            af[i] = *(const short8*)(la + r * (BK * 2) + ((lq ^ ((r >> 1) & 3)) << 4));
        }
#pragma unroll
        for (int j = 0; j < 2; ++j) {
            int r = wn * 32 + j * 16 + l15;
            bq[j] = *(const short8*)(lb + r * (BK * 2) + ((lq ^ ((r >> 1) & 3)) << 4));
        }
#pragma unroll
        for (int i = 0; i < 4; ++i)
#pragma unroll
            for (int j = 0; j < 2; ++j)
                acc[i][j] = __builtin_amdgcn_mfma_f32_16x16x32_bf16(af[i], bq[j], acc[i][j], 0, 0, 0);
    };

    const float* Srow = S + (size_t)tn * SN;   // scale col for global step g: g>>2

    // register double-buffers (named, statically indexed — no scratch)
    f32x4 rwX[2], rwY[2];        // W: X consumed on even steps, Y on odd
    f32x4 raX[2], raY[2];        // A (AMODE 0 only)

    // ---- prologue
    if (AMODE) AGL(g0, 0); else ALD(g0, raX);
    WLD(g0, rwX);
    WRITES(0, rwX, raX, Srow[g0 >> 2]);            // tile 0 into buf0
    if (AMODE == 0) { ALD(g0 + 1, raX); ALD(g0 + 2, raY); }
    WLD(g0 + 1, rwX);                               // W(1) -> X
    WLD(g0 + 2, rwY);                               // W(2) -> Y
    __syncthreads();

    // ---- main loop: all VMEM issued at step top, then compute, then barrier
    for (int kt = 0; kt < STEPS; kt += 2) {
        // ---- even sub-step: cur=0, nxt=1, consumes X(W(kt+1)), refills X(W(kt+3))
        {
            const int kn = g0 + kt + 1;
            const int kf = (kt + 3 < STEPS) ? g0 + kt + 3 : g0 + STEPS - 1;
            if (kt + 1 < STEPS) {
                WRITES(1, rwX, raX, Srow[kn >> 2]);   // W regs loaded 2 steps ago
                if (AMODE) AGL(kn, 1);
            }
            WLD(kf, rwX);
            if (AMODE == 0) ALD(kf, raX);
            COMPUTE(0);
            __syncthreads();
        }
        // ---- odd sub-step: cur=1, nxt=0, consumes Y(W(kt+2)), refills Y(W(kt+4))
        {
            const int kn = g0 + kt + 2;
            const int kf = (kt + 4 < STEPS) ? g0 + kt + 4 : g0 + STEPS - 1;
            if (kt + 2 < STEPS) {
                WRITES(0, rwY, raY, Srow[kn >> 2]);
                if (AMODE) AGL(kn, 0);
            }
            WLD(kf, rwY);
            if (AMODE == 0) ALD(kf, raY);
            COMPUTE(1);
            __syncthreads();
        }
    }

    // ---- epilogue: C/D layout col=lane&15, row=(lane>>4)*4+r; atomic K-merge
    float* Cb = C + (size_t)(m0 + wm * 64) * NDIM + (n0 + wn * 32);
    const int crow = lq * 4;
#pragma unroll
    for (int i = 0; i < 4; ++i) {
#pragma unroll
        for (int r = 0; r < 4; ++r) {
            float* Cr = Cb + (size_t)(i * 16 + crow + r) * NDIM + l15;
#pragma unroll
            for (int j = 0; j < 2; ++j)
                atomicAdd(&Cr[j * 16], acc[i][j][r]);
        }
    }
}

extern "C" void kernel_launch(void* const* d_in, const int* in_sizes, int n_in,
                              void* d_out, int out_size, void* d_ws, size_t ws_size,
                              hipStream_t stream) {
    const float* inp = (const float*)d_in[0];   // [1,512,7168] fp32
    const float* w   = (const float*)d_in[1];   // [18432,7168] fp32
    const float* s   = (const float*)d_in[2];   // [144,56] fp32
    float* out       = (float*)d_out;           // [1,512,18432] fp32

    int M = in_sizes[0] / KDIM;                 // 512
    dim3 grid((M / BM) * (NDIM / BN), SPLITK);  // 576 x 2
    int nunits = (M / BM) * NT32 * 512;
    size_t need = (size_t)nunits * 16;

    hipMemsetAsync(out, 0, (size_t)out_size * sizeof(float), stream);

    if (ws_size >= need) {
        __hip_bfloat16* abt = (__hip_bfloat16*)d_ws;
        hipLaunchKernelGGL(a_permute, dim3((nunits + 255) / 256), dim3(256), 0, stream,
                           inp, abt, nunits);
        hipLaunchKernelGGL((fp8lin_gemm<1>), grid, dim3(512), 0, stream,
                           inp, (const char*)abt, w, s, out, M);
    } else {
        hipLaunchKernelGGL((fp8lin_gemm<0>), grid, dim3(512), 0, stream,
                           inp, (const char*)nullptr, w, s, out, M);
    }
}

// Round 16
// 633.158 us; speedup vs baseline: 1.1454x; 1.1454x over previous
//
#include <hip/hip_runtime.h>
#include <hip/hip_bf16.h>

typedef __attribute__((ext_vector_type(8))) short short8;
typedef __attribute__((ext_vector_type(4))) float f32x4;

#define BM 128
#define BN 128
#define BK 64
#define KDIM 7168
#define NDIM 18432
#define SN 56            // KDIM/128 scale cols
#define NTK 112          // KDIM/BK
#define SPLITK 2
#define STEPS (NTK / SPLITK)   // 56 per block

static __device__ __forceinline__ short bfb(float f) {
    __hip_bfloat16 h = __float2bfloat16(f);
    return __builtin_bit_cast(short, h);
}

// ---- pre-kernel: A fp32 -> bf16, BK=64-tile-major, inverse-XOR-swizzled so
// the GEMM stages it with global_load_lds (linear dest) and reads with XOR.
// unit g = ((mt*NTK + kt)*1024 + r*8 + slot); content = A[mt*128+r][kt*64 + (slot^(r&7))*8 .. +8)
extern "C" __global__ void __launch_bounds__(256)
a_permute(const float* __restrict__ A, __hip_bfloat16* __restrict__ Abt, int nunits) {
    int g = blockIdx.x * blockDim.x + threadIdx.x;
    if (g >= nunits) return;
    int u    = g & 1023;
    int t    = g >> 10;
    int ktt  = t % NTK;
    int mt   = t / NTK;
    int r    = u >> 3;
    int slot = u & 7;
    int row  = mt * BM + r;
    int col  = ktt * BK + ((slot ^ (r & 7)) << 3);
    const float* p = A + (size_t)row * KDIM + col;
    f32x4 v0 = *(const f32x4*)p;
    f32x4 v1 = *(const f32x4*)(p + 4);
    short8 o;
#pragma unroll
    for (int j = 0; j < 4; ++j) { o[j] = bfb(v0[j]); o[j + 4] = bfb(v1[j]); }
    *(short8*)(Abt + (size_t)g * 8) = o;
}

// W never touches LDS: each wave loads its own B-fragment rows directly from
// global (16 rows x 128B contiguous per instr), dequants in registers.
// A via global_load_lds from pre-permuted Abt (AMODE 1) or reg-staged (AMODE 0).
// Split-K=2 over blockIdx.y; partials atomicAdd'ed into zeroed C.
template <int AMODE>
__global__ void __launch_bounds__(512, 4)
fp8lin_gemm(const float* __restrict__ A,          // [M][K] fp32
            const char*  __restrict__ Abt,        // pre-permuted bf16 tiles (ws)
            const float* __restrict__ W,          // [N][K] fp32
            const float* __restrict__ S,          // [N/128][K/128]
            float* __restrict__ C,                // [M][N], pre-zeroed
            int M)
{
    const int ntile_m = M / BM;            // 4
    const int ntile_n = NDIM / BN;         // 144
    const int nwg = ntile_m * ntile_n;     // 576

    int orig = (int)blockIdx.x;
    int q = nwg >> 3;
    int lid = (orig & 7) * q + (orig >> 3);

    const int tm = lid % ntile_m;
    const int tn = lid / ntile_m;
    const int kh = blockIdx.y;             // K-half
    const int m0 = tm * BM;
    const int n0 = tn * BN;
    const int g0 = kh * STEPS;             // first global K-step

    const int tid  = threadIdx.x;
    const int lane = tid & 63;
    const int wid  = tid >> 6;      // 8 waves: 2(M) x 4(N), wave tile 64x32
    const int wm   = wid >> 2;
    const int wn   = wid & 3;

    __shared__ char ldsA[2][BM * BK * 2];   // bf16 A tiles, 16 KiB each (32 KiB)

    const int l15 = lane & 15;
    const int lq  = lane >> 4;      // 16B chunk quarter

    auto AGL = [&](int gstep, int buf) {   // async A: global -> LDS, 2 inst/wave
        const char* src = Abt + (((size_t)(tm * NTK + gstep)) << 14);
#pragma unroll
        for (int c = 0; c < 2; ++c) {
            int ub = wid * 128 + c * 64;
            __builtin_amdgcn_global_load_lds(
                (const __attribute__((address_space(1))) void*)(src + (size_t)(ub + lane) * 16),
                (__attribute__((address_space(3))) void*)(&ldsA[buf][ub * 16]),
                16, 0, 0);
        }
    };

    // AMODE 0 fallback: reg-stage A (2 units/thread) with write-side swizzle
    auto ASTAGE = [&](int gstep, int buf) {
#pragma unroll
        for (int c = 0; c < 2; ++c) {
            int u  = c * 512 + tid;
            int r  = u >> 3;
            int sl = u & 7;
            const float* pa = A + (size_t)(m0 + r) * KDIM + gstep * BK + sl * 8;
            f32x4 v0 = *(const f32x4*)pa;
            f32x4 v1 = *(const f32x4*)(pa + 4);
            short8 va;
#pragma unroll
            for (int j = 0; j < 4; ++j) { va[j] = bfb(v0[j]); va[j + 4] = bfb(v1[j]); }
            *(short8*)(&ldsA[buf][r * (BK * 2) + ((sl ^ (r & 7)) << 4)]) = va;
        }
    };

    // W fragment lane bases: row n0 + wn*32 + j*16 + l15
    const float* W0 = W + (size_t)(n0 + wn * 32 + l15) * KDIM;
    const float* W1 = W0 + (size_t)16 * KDIM;

    f32x4 FA[4], FB[4];     // fp32-staged W frags: [j*2 + half], 16 VGPR each

    auto WISSUE = [&](int g, int kk, f32x4* F) {
        const size_t col = (size_t)g * BK + kk * 32 + lq * 8;
        F[0] = *(const f32x4*)(W0 + col);
        F[1] = *(const f32x4*)(W0 + col + 4);
        F[2] = *(const f32x4*)(W1 + col);
        F[3] = *(const f32x4*)(W1 + col + 4);
    };

    auto WCVT = [&](const f32x4* F, float s, short8* bq) {
#pragma unroll
        for (int j = 0; j < 2; ++j) {
#pragma unroll
            for (int e = 0; e < 4; ++e) {
                bq[j][e]     = bfb(F[j * 2][e] * s);
                bq[j][e + 4] = bfb(F[j * 2 + 1][e] * s);
            }
        }
    };

    auto ARD = [&](int buf, int kk, short8* af) {
        const char* la = ldsA[buf];
        const int kc = kk * 4 + lq;
#pragma unroll
        for (int i = 0; i < 4; ++i) {
            int r = wm * 64 + i * 16 + l15;
            af[i] = *(const short8*)(la + r * (BK * 2) + ((kc ^ (r & 7)) << 4));
        }
    };

    f32x4 acc[4][2];
#pragma unroll
    for (int i = 0; i < 4; ++i)
#pragma unroll
        for (int j = 0; j < 2; ++j)
            acc[i][j] = f32x4{0.f, 0.f, 0.f, 0.f};

    const float* Srow = S + (size_t)tn * SN;

    // ---- prologue: A tile g0 -> buf0; W(g0,kk0) -> FA
    if (AMODE) AGL(g0, 0); else ASTAGE(g0, 0);
    WISSUE(g0, 0, FA);
    __syncthreads();

    // ---- main loop
    for (int kt = 0; kt < STEPS; ++kt) {
        const int cur = kt & 1;
        const int nxt = cur ^ 1;
        const int g   = g0 + kt;
        const float s = Srow[g >> 1];

        // sub0: issue kk1 W loads; compute kk0
        WISSUE(g, 1, FB);
        {
            short8 bq[2], af[4];
            WCVT(FA, s, bq);
            ARD(cur, 0, af);
#pragma unroll
            for (int i = 0; i < 4; ++i)
#pragma unroll
                for (int j = 0; j < 2; ++j)
                    acc[i][j] = __builtin_amdgcn_mfma_f32_16x16x32_bf16(af[i], bq[j], acc[i][j], 0, 0, 0);
        }

        // sub1: AGL first, then next-step W loads (stay in flight across barrier)
        if (kt + 1 < STEPS) {
            if (AMODE) AGL(g + 1, nxt); else ASTAGE(g + 1, nxt);
            WISSUE(g + 1, 0, FA);
        }
        {
            short8 bq[2], af[4];
            WCVT(FB, s, bq);
            ARD(cur, 1, af);
#pragma unroll
            for (int i = 0; i < 4; ++i)
#pragma unroll
                for (int j = 0; j < 2; ++j)
                    acc[i][j] = __builtin_amdgcn_mfma_f32_16x16x32_bf16(af[i], bq[j], acc[i][j], 0, 0, 0);
        }

        // counted-vmcnt barrier: AGL done (issued before the 4 FA loads),
        // FA loads may stay in flight; lgkm drained (ds ops).
        __builtin_amdgcn_sched_barrier(0);
        asm volatile("s_waitcnt vmcnt(4) lgkmcnt(0)" ::: "memory");
        __builtin_amdgcn_s_barrier();
    }

    // ---- epilogue: C/D layout col=lane&15, row=(lane>>4)*4+r; atomic K-merge
    float* Cb = C + (size_t)(m0 + wm * 64) * NDIM + (n0 + wn * 32);
    const int crow = lq * 4;
#pragma unroll
    for (int i = 0; i < 4; ++i) {
#pragma unroll
        for (int r = 0; r < 4; ++r) {
            float* Cr = Cb + (size_t)(i * 16 + crow + r) * NDIM + l15;
#pragma unroll
            for (int j = 0; j < 2; ++j)
                atomicAdd(&Cr[j * 16], acc[i][j][r]);
        }
    }
}

extern "C" void kernel_launch(void* const* d_in, const int* in_sizes, int n_in,
                              void* d_out, int out_size, void* d_ws, size_t ws_size,
                              hipStream_t stream) {
    const float* inp = (const float*)d_in[0];   // [1,512,7168] fp32
    const float* w   = (const float*)d_in[1];   // [18432,7168] fp32
    const float* s   = (const float*)d_in[2];   // [144,56] fp32
    float* out       = (float*)d_out;           // [1,512,18432] fp32

    int M = in_sizes[0] / KDIM;                 // 512
    dim3 grid((M / BM) * (NDIM / BN), SPLITK);  // 576 x 2
    int nunits = (M / BM) * NTK * 1024;
    size_t need = (size_t)nunits * 16;

    hipMemsetAsync(out, 0, (size_t)out_size * sizeof(float), stream);

    if (ws_size >= need) {
        __hip_bfloat16* abt = (__hip_bfloat16*)d_ws;
        hipLaunchKernelGGL(a_permute, dim3((nunits + 255) / 256), dim3(256), 0, stream,
                           inp, abt, nunits);
        hipLaunchKernelGGL((fp8lin_gemm<1>), grid, dim3(512), 0, stream,
                           inp, (const char*)abt, w, s, out, M);
    } else {
        hipLaunchKernelGGL((fp8lin_gemm<0>), grid, dim3(512), 0, stream,
                           inp, (const char*)nullptr, w, s, out, M);
    }
}

// Round 17
// 324.215 us; speedup vs baseline: 2.2368x; 1.9529x over previous
//
#include <hip/hip_runtime.h>
#include <hip/hip_bf16.h>

typedef __attribute__((ext_vector_type(8))) short short8;
typedef __attribute__((ext_vector_type(4))) float f32x4;

#define BM 128
#define BN 128
#define BK 64
#define KDIM 7168
#define NDIM 18432
#define SN 56            // KDIM/128 scale cols
#define NTK 112          // KDIM/BK

static __device__ __forceinline__ short bfb(float f) {
    __hip_bfloat16 h = __float2bfloat16(f);
    return __builtin_bit_cast(short, h);
}

// ---- pre-kernel: A fp32 -> bf16, tile-major, inverse-XOR-swizzled so the
// GEMM can global_load_lds it linearly and read with the XOR formula.
extern "C" __global__ void __launch_bounds__(256)
a_permute(const float* __restrict__ A, __hip_bfloat16* __restrict__ Abt, int nunits) {
    int g = blockIdx.x * blockDim.x + threadIdx.x;
    if (g >= nunits) return;
    int u    = g & 1023;
    int t    = g >> 10;
    int ktt  = t % NTK;
    int mt   = t / NTK;
    int r    = u >> 3;
    int slot = u & 7;
    int row  = mt * BM + r;
    int col  = ktt * BK + ((slot ^ (r & 7)) << 3);
    const float* p = A + (size_t)row * KDIM + col;
    f32x4 v0 = *(const f32x4*)p;
    f32x4 v1 = *(const f32x4*)(p + 4);
    short8 o;
#pragma unroll
    for (int j = 0; j < 4; ++j) { o[j] = bfb(v0[j]); o[j + 4] = bfb(v1[j]); }
    *(short8*)(Abt + (size_t)g * 8) = o;
}

// R4 structure (best measured: 335us GEMM) with ONE change: counted-vmcnt
// barrier (vmcnt(4)) so next-step W loads ride across the barrier instead of
// being drained by __syncthreads' vmcnt(0). No sched_barrier (m141 lesson).
template <int AMODE>
__global__ void __launch_bounds__(512, 4)
fp8lin_gemm(const float* __restrict__ A,              // [M][K] fp32
            const char*  __restrict__ Abt,            // pre-permuted bf16 (ws)
            const float* __restrict__ W,              // [N][K] fp32
            const float* __restrict__ S,              // [N/128][K/128]
            float* __restrict__ C,                    // [M][N]
            int M)
{
    const int ntile_m = M / BM;            // 4
    const int ntile_n = NDIM / BN;         // 144
    const int nwg = ntile_m * ntile_n;     // 576

    int orig = (int)blockIdx.x;
    int q = nwg >> 3;
    int lid = (orig & 7) * q + (orig >> 3);

    const int tm = lid % ntile_m;
    const int tn = lid / ntile_m;
    const int m0 = tm * BM;
    const int n0 = tn * BN;

    const int tid  = threadIdx.x;
    const int lane = tid & 63;
    const int wid  = tid >> 6;      // 8 waves: 2(M) x 4(N), wave tile 64x32
    const int wm   = wid >> 2;
    const int wn   = wid & 3;

    __shared__ char ldsA[2][BM * BK * 2];   // bf16 A tiles, 16 KiB each
    __shared__ char ldsW[2][BN * BK * 2];   // bf16 dequant W tiles, 16 KiB each

    int st_row[2], st_kc[2], st_byte[2];
#pragma unroll
    for (int c = 0; c < 2; ++c) {
        int u = c * 512 + tid;
        int r  = u >> 3;
        int kc = u & 7;
        st_row[c]  = r;
        st_kc[c]   = kc;
        st_byte[c] = r * (BK * 2) + ((kc << 4) ^ ((r & 7) << 4));
    }

    const float* Afp = A + (size_t)m0 * KDIM;
    const float* Wb  = W + (size_t)n0 * KDIM;

    f32x4 rw[2][2];        // W fp32 staging
    f32x4 rafp[2][2];      // A fp32 staging (AMODE 0 only)

    auto AGL = [&](int kt_, int buf) {   // async A: global -> LDS, 2 insts/wave
        const char* src = Abt + (((size_t)(tm * NTK + kt_)) << 14);
#pragma unroll
        for (int c = 0; c < 2; ++c) {
            int ub = wid * 128 + c * 64;
            __builtin_amdgcn_global_load_lds(
                (const __attribute__((address_space(1))) void*)(src + (size_t)(ub + lane) * 16),
                (__attribute__((address_space(3))) void*)(&ldsA[buf][ub * 16]),
                16, 0, 0);
        }
    };

    auto WLD = [&](int kt_) {            // W fp32 -> regs (4 x dwordx4)
        const int kof = kt_ * BK;
#pragma unroll
        for (int c = 0; c < 2; ++c) {
            const float* pw = Wb + (size_t)st_row[c] * KDIM + kof + st_kc[c] * 8;
            rw[c][0] = *(const f32x4*)pw;
            rw[c][1] = *(const f32x4*)(pw + 4);
        }
    };

    auto ALD = [&](int kt_) {            // AMODE 0: A fp32 -> regs
        const int kof = kt_ * BK;
#pragma unroll
        for (int c = 0; c < 2; ++c) {
            const float* pa = Afp + (size_t)st_row[c] * KDIM + kof + st_kc[c] * 8;
            rafp[c][0] = *(const f32x4*)pa;
            rafp[c][1] = *(const f32x4*)(pa + 4);
        }
    };

    auto WRITES = [&](int buf, float s) {
#pragma unroll
        for (int c = 0; c < 2; ++c) {
            short8 vw;
#pragma unroll
            for (int j = 0; j < 4; ++j) {
                vw[j]     = bfb(rw[c][0][j] * s);
                vw[j + 4] = bfb(rw[c][1][j] * s);
            }
            *(short8*)(&ldsW[buf][st_byte[c]]) = vw;
            if (AMODE == 0) {
                short8 va;
#pragma unroll
                for (int j = 0; j < 4; ++j) {
                    va[j]     = bfb(rafp[c][0][j]);
                    va[j + 4] = bfb(rafp[c][1][j]);
                }
                *(short8*)(&ldsA[buf][st_byte[c]]) = va;
            }
        }
    };

    f32x4 acc[4][2];
#pragma unroll
    for (int i = 0; i < 4; ++i)
#pragma unroll
        for (int j = 0; j < 2; ++j)
            acc[i][j] = f32x4{0.f, 0.f, 0.f, 0.f};

    const int l15 = lane & 15;
    const int lq  = lane >> 4;

    auto COMPUTE = [&](int buf) {
        const char* la = ldsA[buf];
        const char* lb = ldsW[buf];
#pragma unroll
        for (int kk = 0; kk < 2; ++kk) {
            int kc = kk * 4 + lq;
            short8 af[4], bq[2];
#pragma unroll
            for (int i = 0; i < 4; ++i) {
                int r = wm * 64 + i * 16 + l15;
                af[i] = *(const short8*)(la + r * (BK * 2) + ((kc << 4) ^ ((r & 7) << 4)));
            }
#pragma unroll
            for (int j = 0; j < 2; ++j) {
                int r = wn * 32 + j * 16 + l15;
                bq[j] = *(const short8*)(lb + r * (BK * 2) + ((kc << 4) ^ ((r & 7) << 4)));
            }
#pragma unroll
            for (int i = 0; i < 4; ++i)
#pragma unroll
                for (int j = 0; j < 2; ++j)
                    acc[i][j] = __builtin_amdgcn_mfma_f32_16x16x32_bf16(af[i], bq[j], acc[i][j], 0, 0, 0);
        }
    };

    const float* Srow = S + (size_t)tn * SN;

    // ---- prologue (full drain once; negligible)
    if (AMODE) AGL(0, 0); else ALD(0);
    WLD(0);
    WRITES(0, Srow[0]);
    if (AMODE == 0) ALD(1);
    WLD(1);
    __syncthreads();

    // ---- main loop: 2-phase dbuf, distance-2 W prefetch, counted-vmcnt fence
    for (int kt = 0; kt < NTK; ++kt) {
        const int cur = kt & 1;
        const int nxt = cur ^ 1;
        if (AMODE && kt + 1 < NTK) AGL(kt + 1, nxt);      // issued FIRST
        COMPUTE(cur);
        if (kt + 1 < NTK) {
            WRITES(nxt, Srow[(kt + 1) >> 1]);             // consumes WLD(kt+1)
            if (kt + 2 < NTK) { if (AMODE == 0) ALD(kt + 2); WLD(kt + 2); }
        }
        if (kt + 2 < NTK) {
            // outstanding: AGL(kt+1)=2 (oldest) + WLD(kt+2)=4 (newest).
            // vmcnt(4): AGL drained (LDS ready), W loads stay in flight.
            asm volatile("s_waitcnt vmcnt(4) lgkmcnt(0)" ::: "memory");
            __builtin_amdgcn_s_barrier();
        } else {
            // tail: no fresh WLD issued -> drain everything once.
            asm volatile("s_waitcnt vmcnt(0) lgkmcnt(0)" ::: "memory");
            __builtin_amdgcn_s_barrier();
        }
    }

    // ---- epilogue: C/D layout col=lane&15, row=(lane>>4)*4+r
    float* Cb = C + (size_t)(m0 + wm * 64) * NDIM + (n0 + wn * 32);
    const int crow = lq * 4;
#pragma unroll
    for (int i = 0; i < 4; ++i) {
#pragma unroll
        for (int r = 0; r < 4; ++r) {
            float* Cr = Cb + (size_t)(i * 16 + crow + r) * NDIM + l15;
#pragma unroll
            for (int j = 0; j < 2; ++j)
                Cr[j * 16] = acc[i][j][r];
        }
    }
}

extern "C" void kernel_launch(void* const* d_in, const int* in_sizes, int n_in,
                              void* d_out, int out_size, void* d_ws, size_t ws_size,
                              hipStream_t stream) {
    const float* inp = (const float*)d_in[0];   // [1,512,7168] fp32
    const float* w   = (const float*)d_in[1];   // [18432,7168] fp32
    const float* s   = (const float*)d_in[2];   // [144,56] fp32
    float* out       = (float*)d_out;           // [1,512,18432] fp32

    int M = in_sizes[0] / KDIM;                 // 512
    int grid = (M / BM) * (NDIM / BN);          // 576
    int nunits = (M / BM) * NTK * 1024;
    size_t need = (size_t)nunits * 16;

    if (ws_size >= need) {
        __hip_bfloat16* abt = (__hip_bfloat16*)d_ws;
        hipLaunchKernelGGL(a_permute, dim3((nunits + 255) / 256), dim3(256), 0, stream,
                           inp, abt, nunits);
        hipLaunchKernelGGL((fp8lin_gemm<1>), dim3(grid), dim3(512), 0, stream,
                           inp, (const char*)abt, w, s, out, M);
    } else {
        hipLaunchKernelGGL((fp8lin_gemm<0>), dim3(grid), dim3(512), 0, stream,
                           inp, (const char*)nullptr, w, s, out, M);
    }
}